// Round 7
// baseline (260.495 us; speedup 1.0000x reference)
//
#include <hip/hip_runtime.h>

// DoReFa dense: out = q_in(3-bit) @ (sign(W)*E) + b,  E = mean|W|
//   out[i,j] = (E/7) * sum_k r[i,k]*sign(W[k,j]),  r in 0..7 -- exact in i8 MFMA.
// R7: A-only LDS (B direct global->reg, wave-private, 1-tile-ahead ping-pong);
//     software-pipelined frag reads (operands requested 1 group early, cross-tile
//     a0/a1 prefetch); correctly-counted SGB [6 VMEM][2 DS][8 MFMA]x4;
//     4 LDS buffers, 3-tile stage lead, vmcnt(2) gate, 1 barrier/tile.

static constexpr int BATCH  = 8192;
static constexpr int IN_CH  = 4096;
static constexpr int NUNITS = 4096;
static constexpr int TPB    = 256;

typedef int v4i __attribute__((ext_vector_type(4)));

// ---- workspace layout ----
static constexpr size_t A8_OFF   = 0;
static constexpr size_t A8_BYTES = (size_t)BATCH * IN_CH;    // 32 MB
static constexpr size_t BT_OFF   = A8_OFF + A8_BYTES;
static constexpr size_t BT_BYTES = (size_t)NUNITS * IN_CH;   // 16 MB
static constexpr int    NPART    = 4096;
static constexpr size_t PART_OFF = BT_OFF + BT_BYTES;
static constexpr size_t SCALE_OFF= PART_OFF + NPART * sizeof(float);

// ------------------------------------------------------------- scale finalize
__global__ __launch_bounds__(TPB) void k_scale(const float* __restrict__ partials,
                                               float* __restrict__ scale) {
    __shared__ float red[TPB];
    float s = 0.f;
    for (int i = threadIdx.x; i < NPART; i += TPB) s += partials[i];
    red[threadIdx.x] = s;
    __syncthreads();
    for (int off = TPB / 2; off > 0; off >>= 1) {
        if ((int)threadIdx.x < off) red[threadIdx.x] += red[threadIdx.x + off];
        __syncthreads();
    }
    if (threadIdx.x == 0) {
        float E = red[0] / (float)((size_t)IN_CH * NUNITS);
        *scale = E / 7.0f;
    }
}

// ------------------------------------------------------------- quantize A
__device__ __forceinline__ unsigned int q4(float4 v) {
    unsigned int b0 = (unsigned int)(int)rintf(fminf(1.0f, fabsf(v.x)) * 7.0f);
    unsigned int b1 = (unsigned int)(int)rintf(fminf(1.0f, fabsf(v.y)) * 7.0f);
    unsigned int b2 = (unsigned int)(int)rintf(fminf(1.0f, fabsf(v.z)) * 7.0f);
    unsigned int b3 = (unsigned int)(int)rintf(fminf(1.0f, fabsf(v.w)) * 7.0f);
    return b0 | (b1 << 8) | (b2 << 16) | (b3 << 24);
}

__global__ __launch_bounds__(TPB) void k_quant_a(const float4* __restrict__ x4,
                                                 uint4* __restrict__ a16) {
    const size_t t = (size_t)blockIdx.x * TPB + threadIdx.x;
    uint4 o;
    o.x = q4(x4[t * 4 + 0]);
    o.y = q4(x4[t * 4 + 1]);
    o.z = q4(x4[t * 4 + 2]);
    o.w = q4(x4[t * 4 + 3]);
    a16[t] = o;
}

// -------------------------- sign(W) transpose to [N][K]  +  fused |W| partial sum
__global__ __launch_bounds__(TPB) void k_signT(const float* __restrict__ W,
                                               char* __restrict__ bt,
                                               float* __restrict__ partials) {
    __shared__ char tile[64][68];
    __shared__ float red[TPB];
    const int bk = blockIdx.x & 63;
    const int bn = blockIdx.x >> 6;
    const int t  = threadIdx.x;
    const int c  = t & 63;
    const int r0 = t >> 6;
    float asum = 0.f;
#pragma unroll
    for (int i = 0; i < 16; ++i) {
        int r = i * 4 + r0;
        float w = W[(size_t)(bk * 64 + r) * NUNITS + bn * 64 + c];
        asum += fabsf(w);
        tile[c][r] = (w > 0.f) ? 1 : ((w < 0.f) ? -1 : 0);
    }
    __syncthreads();
    const int n  = t >> 2;
    const int kk = (t & 3) * 16;
    char o[16];
#pragma unroll
    for (int j = 0; j < 16; ++j) o[j] = tile[n][kk + j];
    *(uint4*)(bt + (size_t)(bn * 64 + n) * IN_CH + bk * 64 + kk) = *(const uint4*)o;

    red[t] = asum;
    __syncthreads();
    for (int off = TPB / 2; off > 0; off >>= 1) {
        if (t < off) red[t] += red[t + off];
        __syncthreads();
    }
    if (t == 0) partials[blockIdx.x] = red[0];
}

// ---------------------------------------------------------------- GEMM
// 256x256 block tile, BK=64, 8 waves (2Mx4N), mfma_i32_16x16x64_i8.
// LDS = A only: 4 buffers x [128 lines x 128B]; line L = A-row L (left 64B) ||
// A-row L+128 (right 64B); 16B slot ^= (line&7). B loads go straight to VGPR.
__device__ __forceinline__ void gload_lds16(const void* g, void* l) {
    __builtin_amdgcn_global_load_lds((const __attribute__((address_space(1))) void*)g,
                                     (__attribute__((address_space(3))) void*)l,
                                     16, 0, 0);
}

#define VMCNT2   asm volatile("s_waitcnt vmcnt(2)" ::: "memory")
#define VMCNT0   asm volatile("s_waitcnt vmcnt(0)" ::: "memory")
#define BARRIER  __builtin_amdgcn_s_barrier()
#define PRIO1    __builtin_amdgcn_s_setprio(1)
#define PRIO0    __builtin_amdgcn_s_setprio(0)
#define SGB(mask, n) __builtin_amdgcn_sched_group_barrier((mask), (n), 0)

static constexpr int NT = IN_CH / 64;   // 64 K-tiles

__global__ __launch_bounds__(512, 2) void k_gemm(const char* __restrict__ A8,
                                                 const char* __restrict__ BT,
                                                 const float* __restrict__ scale_p,
                                                 const float* __restrict__ bias,
                                                 float* __restrict__ out) {
    __shared__ char Aflat[4 * 16384];   // 64 KiB

    const int t    = threadIdx.x;
    const int bid  = blockIdx.x;                  // 512 blocks
    const int swzb = (bid & 7) * 64 + (bid >> 3); // XCD swizzle (bijective)
    const int bRow = swzb >> 4;                   // 0..31
    const int bCol = swzb & 15;                   // 0..15
    const int lane = t & 63;
    const int wid  = t >> 6;
    const int wm   = wid >> 2;                    // 0..1
    const int wn   = wid & 3;                     // 0..3
    const int lr   = lane & 15;
    const int lk4  = lane >> 4;                   // 0..3

    const size_t aBase = (size_t)(bRow * 256) * IN_CH;

    // frag read: A row (wm*128 + i*16 + lr) -> line i*16+lr, logical slot wm*4+lk4,
    // physical slot = logical ^ (line&7); line&7 == lr&7.
    const int aoff = (((wm * 4 + lk4) ^ (lr & 7)) << 4);
#define RD(buf, i) (*(const v4i*)((buf) + (((i) * 16 + lr) * 128) + aoff))

    // staging: dest = buf + h*8192 + t*16 (linear); that dest is line h*64+(t>>3),
    // phys slot t&7 -> logical slot s_log = (t&7) ^ ((t>>3)&7); source row/col:
    const int s_log   = (t & 7) ^ ((t >> 3) & 7);
    const int rowbase = ((s_log >> 2) << 7) + (t >> 3);      // half*128 + line%128
    const char* sA    = A8 + aBase + (size_t)rowbase * IN_CH + ((s_log & 3) << 4);

    // B direct-to-reg: wave-private rows (bCol*256 + wn*64 + n*16 + lr), 16B at lk4*16
    const char* bptr = BT + ((size_t)(bCol * 256 + wn * 64 + lr)) * IN_CH + (lk4 << 4);

    v4i acc[8][4] = {};
    v4i bA[4], bB[4];
    v4i ap0, ap1;

#define MFMA8(x, y, m0, B)                                                       \
    PRIO1;                                                                       \
    _Pragma("unroll") for (int n = 0; n < 4; ++n) {                              \
        acc[(m0)][n]     = __builtin_amdgcn_mfma_i32_16x16x64_i8((x), B[n], acc[(m0)][n], 0, 0, 0);     \
        acc[(m0) + 1][n] = __builtin_amdgcn_mfma_i32_16x16x64_i8((y), B[n], acc[(m0) + 1][n], 0, 0, 0); \
    }                                                                            \
    PRIO0

#define STAGEA(kt)                                                               \
    _Pragma("unroll") for (int h = 0; h < 2; ++h)                                \
        gload_lds16(sA + (size_t)h * 64 * IN_CH + (size_t)(kt) * 64,             \
                    Aflat + (((kt) & 3) << 14) + h * 8192 + t * 16)

#define LOADB(BN, kt)                                                            \
    _Pragma("unroll") for (int n = 0; n < 4; ++n)                                \
        BN[n] = *(const v4i*)(bptr + (size_t)n * 16 * IN_CH + (size_t)(kt) * 64)

// One K-tile. DOB: load b(T+1) into BN. DOSTG: stage A(T+3). DOPF: ds-prefetch
// a0,a1 of tile T+1. GATE: vmcnt. DOSGB: pin [6 VMEM][2 DS][8 MFMA]x4.
#define BODY(T, BC, BN, DOB, DOSTG, DOPF, GATE, DOSGB)                           \
    {                                                                            \
        const char* cur = Aflat + (((T) & 3) << 14);                             \
        if (DOB) { LOADB(BN, (T) + 1); }                                         \
        if (DOSTG) { STAGEA((T) + 3); }                                          \
        v4i a2 = RD(cur, 2), a3 = RD(cur, 3);                                    \
        MFMA8(ap0, ap1, 0, BC);                                                  \
        v4i a4 = RD(cur, 4), a5 = RD(cur, 5);                                    \
        MFMA8(a2, a3, 2, BC);                                                    \
        v4i a6 = RD(cur, 6), a7 = RD(cur, 7);                                    \
        MFMA8(a4, a5, 4, BC);                                                    \
        if (DOPF) { const char* nb = Aflat + ((((T) + 1) & 3) << 14);            \
                    ap0 = RD(nb, 0); ap1 = RD(nb, 1); }                          \
        MFMA8(a6, a7, 6, BC);                                                    \
        if (DOSGB) { SGB(0x10, 6);                                               \
                     SGB(0x100, 2); SGB(0x8, 8); SGB(0x100, 2); SGB(0x8, 8);     \
                     SGB(0x100, 2); SGB(0x8, 8); SGB(0x100, 2); SGB(0x8, 8); }   \
        GATE;                                                                    \
        BARRIER;                                                                 \
    }

    // ---- prologue: stage A(0..2), load b(0); full drain (one-time); seed ap
    STAGEA(0);
    STAGEA(1);
    STAGEA(2);
    LOADB(bA, 0);
    VMCNT0;
    BARRIER;
    {
        const char* b0 = Aflat;
        ap0 = RD(b0, 0); ap1 = RD(b0, 1);
    }

    // ---- main: tiles 0..59 (full bodies), peeled tail 60..63
    for (int T = 0; T < 60; T += 2) {
        BODY(T,     bA, bB, 1, 1, 1, VMCNT2, 1);
        BODY(T + 1, bB, bA, 1, 1, 1, VMCNT2, 1);
    }
    BODY(60, bA, bB, 1, 1, 1, VMCNT2, 1);   // b(61), stage A(63)
    BODY(61, bB, bA, 1, 0, 1, VMCNT0, 0);   // b(62); drain
    BODY(62, bA, bB, 1, 0, 1, VMCNT0, 0);   // b(63); drain
    BODY(63, bB, bA, 0, 0, 0, (void)0, 0);  // last tile

    // ---- epilogue
    const float scale = *scale_p;
    const int orow0 = bRow * 256 + wm * 128;
    const int ocol0 = bCol * 256 + wn * 64;
#pragma unroll
    for (int m = 0; m < 8; ++m) {
#pragma unroll
        for (int n = 0; n < 4; ++n) {
            const int col = ocol0 + n * 16 + lr;
            const float bb = bias[col];
            const int rbase = orow0 + m * 16 + lk4 * 4;
#pragma unroll
            for (int j = 0; j < 4; ++j)
                out[(size_t)(rbase + j) * NUNITS + col] = scale * (float)acc[m][n][j] + bb;
        }
    }
#undef BODY
#undef LOADB
#undef STAGEA
#undef MFMA8
#undef RD
}

// ---------------------------------------------------------------- launch
extern "C" void kernel_launch(void* const* d_in, const int* in_sizes, int n_in,
                              void* d_out, int out_size, void* d_ws, size_t ws_size,
                              hipStream_t stream) {
    const float* x  = (const float*)d_in[0];
    const float* W  = (const float*)d_in[1];
    const float* b  = (const float*)d_in[2];
    float* out      = (float*)d_out;

    char*  ws       = (char*)d_ws;
    char*  A8       = ws + A8_OFF;
    char*  BT       = ws + BT_OFF;
    float* partials = (float*)(ws + PART_OFF);
    float* scale    = (float*)(ws + SCALE_OFF);

    k_signT<<<(IN_CH / 64) * (NUNITS / 64), TPB, 0, stream>>>(W, BT, partials);
    k_scale<<<1, TPB, 0, stream>>>(partials, scale);
    k_quant_a<<<(BATCH * (IN_CH / 16)) / TPB, TPB, 0, stream>>>((const float4*)x, (uint4*)A8);
    k_gemm<<<(BATCH / 256) * (NUNITS / 256), 512, 0, stream>>>(A8, BT, scale, b, out);
}

// Round 8
// 203.978 us; speedup vs baseline: 1.2771x; 1.2771x over previous
//
#include <hip/hip_runtime.h>

// DoReFa dense: out = q_in(3-bit) @ (sign(W)*E) + b,  E = mean|W|
//   out[i,j] = (E/7) * sum_k r[i,k]*sign(W[k,j]),  r in 0..7 -- exact in i8 MFMA.
// R8: A-only LDS (traffic 160KB->96KB/tile, the measured wall); B pre-packed in
//     MFMA-fragment order by k_signT and loaded global->reg COALESCED (1KB/inst,
//     L2-resident), one tile ahead, register ping-pong. R4 drift structure,
//     3 A-buffers, 1 barrier/tile, vmcnt(6) gate. T1 swizzle + T5 setprio kept.

static constexpr int BATCH  = 8192;
static constexpr int IN_CH  = 4096;
static constexpr int NUNITS = 4096;
static constexpr int TPB    = 256;

typedef int v4i __attribute__((ext_vector_type(4)));

// ---- workspace layout ----
static constexpr size_t A8_OFF   = 0;
static constexpr size_t A8_BYTES = (size_t)BATCH * IN_CH;    // 32 MB
static constexpr size_t BF_OFF   = A8_OFF + A8_BYTES;        // B fragment-packed
static constexpr size_t BF_BYTES = (size_t)NUNITS * IN_CH;   // 16 MB
static constexpr int    NPART    = 4096;
static constexpr size_t PART_OFF = BF_OFF + BF_BYTES;
static constexpr size_t SCALE_OFF= PART_OFF + NPART * sizeof(float);

// ------------------------------------------------------------- scale finalize
__global__ __launch_bounds__(TPB) void k_scale(const float* __restrict__ partials,
                                               float* __restrict__ scale) {
    __shared__ float red[TPB];
    float s = 0.f;
    for (int i = threadIdx.x; i < NPART; i += TPB) s += partials[i];
    red[threadIdx.x] = s;
    __syncthreads();
    for (int off = TPB / 2; off > 0; off >>= 1) {
        if ((int)threadIdx.x < off) red[threadIdx.x] += red[threadIdx.x + off];
        __syncthreads();
    }
    if (threadIdx.x == 0) {
        float E = red[0] / (float)((size_t)IN_CH * NUNITS);
        *scale = E / 7.0f;
    }
}

// ------------------------------------------------------------- quantize A
__device__ __forceinline__ unsigned int q4(float4 v) {
    unsigned int b0 = (unsigned int)(int)rintf(fminf(1.0f, fabsf(v.x)) * 7.0f);
    unsigned int b1 = (unsigned int)(int)rintf(fminf(1.0f, fabsf(v.y)) * 7.0f);
    unsigned int b2 = (unsigned int)(int)rintf(fminf(1.0f, fabsf(v.z)) * 7.0f);
    unsigned int b3 = (unsigned int)(int)rintf(fminf(1.0f, fabsf(v.w)) * 7.0f);
    return b0 | (b1 << 8) | (b2 << 16) | (b3 << 24);
}

__global__ __launch_bounds__(TPB) void k_quant_a(const float4* __restrict__ x4,
                                                 uint4* __restrict__ a16) {
    const size_t t = (size_t)blockIdx.x * TPB + threadIdx.x;
    uint4 o;
    o.x = q4(x4[t * 4 + 0]);
    o.y = q4(x4[t * 4 + 1]);
    o.z = q4(x4[t * 4 + 2]);
    o.w = q4(x4[t * 4 + 3]);
    a16[t] = o;
}

// ----- sign(W) -> B packed in MFMA-fragment order + fused |W| partial sum
// BFRAG[nt][kt][lane][16]: nt = col/16 (0..255), kt = k/64 (0..63);
// element (lane, j) = sign(W[k = kt*64 + (lane>>4)*16 + j][col = nt*16 + (lane&15)])
__global__ __launch_bounds__(TPB) void k_signT(const float* __restrict__ W,
                                               char* __restrict__ bf,
                                               float* __restrict__ partials) {
    __shared__ char tile[64][68];   // [n_local][k_local]
    __shared__ float red[TPB];
    const int bk = blockIdx.x & 63;      // k-block of 64  (= kt)
    const int bn = blockIdx.x >> 6;      // n-block of 64  (= 4 nt)
    const int t  = threadIdx.x;
    const int c  = t & 63;
    const int r0 = t >> 6;
    float asum = 0.f;
#pragma unroll
    for (int i = 0; i < 16; ++i) {
        int r = i * 4 + r0;              // k_local
        float w = W[(size_t)(bk * 64 + r) * NUNITS + bn * 64 + c];
        asum += fabsf(w);
        tile[c][r] = (w > 0.f) ? 1 : ((w < 0.f) ? -1 : 0);
    }
    __syncthreads();
    const int ntl  = t >> 6;             // 0..3
    const int lane = t & 63;
    const int cl   = ntl * 16 + (lane & 15);
    const int k0   = (lane >> 4) * 16;
    char o[16];
#pragma unroll
    for (int j = 0; j < 16; ++j) o[j] = tile[cl][k0 + j];
    *(uint4*)(bf + (((size_t)(bn * 4 + ntl) * 64 + bk) << 10) + lane * 16) = *(const uint4*)o;

    red[t] = asum;
    __syncthreads();
    for (int off = TPB / 2; off > 0; off >>= 1) {
        if (t < off) red[t] += red[t + off];
        __syncthreads();
    }
    if (t == 0) partials[blockIdx.x] = red[0];
}

// ---------------------------------------------------------------- GEMM
// 256x256 block tile, BK=64, 8 waves (2Mx4N), mfma_i32_16x16x64_i8.
// LDS = A only: 3 buffers x [128 lines x 128B]; line L = A-row L (logical slots
// 0-3) || A-row L+128 (slots 4-7); phys slot = logical ^ (line&7). B from global.
__device__ __forceinline__ void gload_lds16(const void* g, void* l) {
    __builtin_amdgcn_global_load_lds((const __attribute__((address_space(1))) void*)g,
                                     (__attribute__((address_space(3))) void*)l,
                                     16, 0, 0);
}

#define VMCNT6   asm volatile("s_waitcnt vmcnt(6)" ::: "memory")
#define VMCNT4   asm volatile("s_waitcnt vmcnt(4)" ::: "memory")
#define NOGATE   do {} while (0)
#define BARRIER  __builtin_amdgcn_s_barrier()
#define PRIO1    __builtin_amdgcn_s_setprio(1)
#define PRIO0    __builtin_amdgcn_s_setprio(0)

__global__ __launch_bounds__(512, 2) void k_gemm(const char* __restrict__ A8,
                                                 const char* __restrict__ BF,
                                                 const float* __restrict__ scale_p,
                                                 const float* __restrict__ bias,
                                                 float* __restrict__ out) {
    __shared__ char Aflat[3 * 16384];   // 48 KiB

    const int t    = threadIdx.x;
    const int bid  = blockIdx.x;                  // 512 blocks
    const int swzb = (bid & 7) * 64 + (bid >> 3); // XCD swizzle (bijective)
    const int bRow = swzb >> 4;                   // 0..31
    const int bCol = swzb & 15;                   // 0..15
    const int lane = t & 63;
    const int wid  = t >> 6;
    const int wm   = wid >> 2;                    // 0..1
    const int wn   = wid & 3;                     // 0..3
    const int lr   = lane & 15;
    const int lk4  = lane >> 4;                   // 0..3

    const size_t aBase = (size_t)(bRow * 256) * IN_CH;

    // A frag read (verified in R7): row wm*128 + i*16 + lr -> line i*16+lr,
    // logical slot wm*4+lk4, phys = logical ^ (lr&7)
    const int aoff = (((wm * 4 + lk4) ^ (lr & 7)) << 4);
#define RD(BUF, i) (*(const v4i*)((BUF) + (((i) * 16 + lr) * 128) + aoff))

    // A staging (verified in R7): dest line h*64+(t>>3), phys slot t&7
    const int s_log   = (t & 7) ^ ((t >> 3) & 7);
    const int rowbase = ((s_log >> 2) << 7) + (t >> 3);
    const char* sA    = A8 + aBase + (size_t)rowbase * IN_CH + ((s_log & 3) << 4);

    // B fragment pointer: nt = bCol*16 + wn*4 + nf; [nt][kt][lane][16]
    const char* bfp = BF + (((size_t)(bCol * 16 + wn * 4) * 64) << 10) + (size_t)lane * 16;

    v4i acc[8][4] = {};
    v4i bA[4], bB[4];

#define STAGEA(kt, STG)                                                          \
    _Pragma("unroll") for (int h = 0; h < 2; ++h)                                \
        gload_lds16(sA + (size_t)h * 64 * IN_CH + (size_t)(kt) * 64,             \
                    (STG) + h * 8192 + t * 16)

#define LOADB(BN, kt)                                                            \
    _Pragma("unroll") for (int nf = 0; nf < 4; ++nf)                             \
        BN[nf] = *(const v4i*)(bfp + (size_t)nf * 65536 + ((size_t)(kt) << 10))

#define MFMA8(x, y, m0, B)                                                       \
    _Pragma("unroll") for (int n = 0; n < 4; ++n) {                              \
        acc[(m0)][n]     = __builtin_amdgcn_mfma_i32_16x16x64_i8((x), B[n], acc[(m0)][n], 0, 0, 0);     \
        acc[(m0) + 1][n] = __builtin_amdgcn_mfma_i32_16x16x64_i8((y), B[n], acc[(m0) + 1][n], 0, 0, 0); \
    }

// Body T: load B(T+1) -> BN; stage A(T+2) -> STG; compute tile T from CUR with BC.
#define BODY(T, CUR, STG, BC, BN, DOB, DOSTG, GATE)                              \
    {                                                                            \
        if (DOB)   { LOADB(BN, (T) + 1); }                                       \
        if (DOSTG) { STAGEA((T) + 2, STG); }                                     \
        v4i a0 = RD(CUR, 0), a1 = RD(CUR, 1);                                    \
        PRIO1;                                                                   \
        MFMA8(a0, a1, 0, BC);                                                    \
        v4i a2 = RD(CUR, 2), a3 = RD(CUR, 3);                                    \
        MFMA8(a2, a3, 2, BC);                                                    \
        v4i a4 = RD(CUR, 4), a5 = RD(CUR, 5);                                    \
        MFMA8(a4, a5, 4, BC);                                                    \
        v4i a6 = RD(CUR, 6), a7 = RD(CUR, 7);                                    \
        MFMA8(a6, a7, 6, BC);                                                    \
        PRIO0;                                                                   \
        GATE;                                                                    \
        BARRIER;                                                                 \
    }

    char* B0 = Aflat;
    char* B1 = Aflat + 16384;
    char* B2 = Aflat + 32768;

    // prologue: stage A(0),A(1); load B(0). outstanding = 2+2+4 = 8;
    // vmcnt(6) drains A(0)'s 2 stages.
    STAGEA(0, B0);
    STAGEA(1, B1);
    LOADB(bA, 0);
    VMCNT6;
    BARRIER;

    // main: tiles 0..59; buffers rotate (T%3, (T+2)%3); B ping-pong even=bA odd=bB.
    for (int T = 0; T < 60; T += 6) {
        BODY(T + 0, B0, B2, bA, bB, 1, 1, VMCNT6);
        BODY(T + 1, B1, B0, bB, bA, 1, 1, VMCNT6);
        BODY(T + 2, B2, B1, bA, bB, 1, 1, VMCNT6);
        BODY(T + 3, B0, B2, bB, bA, 1, 1, VMCNT6);
        BODY(T + 4, B1, B0, bA, bB, 1, 1, VMCNT6);
        BODY(T + 5, B2, B1, bB, bA, 1, 1, VMCNT6);
    }
    // tail: 60..63
    BODY(60, B0, B2, bA, bB, 1, 1, VMCNT6);   // stage A(62), load B(61)
    BODY(61, B1, B0, bB, bA, 1, 1, VMCNT6);   // stage A(63), load B(62); A(62) ready
    BODY(62, B2, B0, bA, bB, 1, 0, VMCNT4);   // load B(63); drain A(63)'s stages
    BODY(63, B0, B0, bB, bA, 0, 0, NOGATE);   // last tile

    // ---- epilogue
    const float scale = *scale_p;
    const int orow0 = bRow * 256 + wm * 128;
    const int ocol0 = bCol * 256 + wn * 64;
#pragma unroll
    for (int m = 0; m < 8; ++m) {
#pragma unroll
        for (int n = 0; n < 4; ++n) {
            const int col = ocol0 + n * 16 + lr;
            const float bb = bias[col];
            const int rbase = orow0 + m * 16 + lk4 * 4;
#pragma unroll
            for (int j = 0; j < 4; ++j)
                out[(size_t)(rbase + j) * NUNITS + col] = scale * (float)acc[m][n][j] + bb;
        }
    }
#undef BODY
#undef MFMA8
#undef LOADB
#undef STAGEA
#undef RD
}

// ---------------------------------------------------------------- launch
extern "C" void kernel_launch(void* const* d_in, const int* in_sizes, int n_in,
                              void* d_out, int out_size, void* d_ws, size_t ws_size,
                              hipStream_t stream) {
    const float* x  = (const float*)d_in[0];
    const float* W  = (const float*)d_in[1];
    const float* b  = (const float*)d_in[2];
    float* out      = (float*)d_out;

    char*  ws       = (char*)d_ws;
    char*  A8       = ws + A8_OFF;
    char*  BF       = ws + BF_OFF;
    float* partials = (float*)(ws + PART_OFF);
    float* scale    = (float*)(ws + SCALE_OFF);

    k_signT<<<(IN_CH / 64) * (NUNITS / 64), TPB, 0, stream>>>(W, BF, partials);
    k_scale<<<1, TPB, 0, stream>>>(partials, scale);
    k_quant_a<<<(BATCH * (IN_CH / 16)) / TPB, TPB, 0, stream>>>((const float4*)x, (uint4*)A8);
    k_gemm<<<(BATCH / 256) * (NUNITS / 256), 512, 0, stream>>>(A8, BF, scale, b, out);
}

// Round 9
// 199.853 us; speedup vs baseline: 1.3034x; 1.0206x over previous
//
#include <hip/hip_runtime.h>

// DoReFa dense: out = q_in(3-bit) @ (sign(W)*E) + b,  E = mean|W|
//   out[i,j] = (E/7) * sum_k r[i,k]*sign(W[k,j]),  r in 0..7 -- exact in i8 MFMA.
// R9: faithful m201 8-phase port. Progressive-consumption half-tile staging
//     (stage into the quarter that died LAST phase), counted vmcnt(6) at
//     end-p3/end-p7 only (airtight force-before-read proof), zero sched_barriers,
//     setprio around each 16-MFMA cluster. T1 XCD swizzle + T2 LDS swizzle kept.

static constexpr int BATCH  = 8192;
static constexpr int IN_CH  = 4096;
static constexpr int NUNITS = 4096;
static constexpr int TPB    = 256;

typedef int v4i __attribute__((ext_vector_type(4)));

// ---- workspace layout ----
static constexpr size_t A8_OFF   = 0;
static constexpr size_t A8_BYTES = (size_t)BATCH * IN_CH;    // 32 MB
static constexpr size_t BT_OFF   = A8_OFF + A8_BYTES;
static constexpr size_t BT_BYTES = (size_t)NUNITS * IN_CH;   // 16 MB
static constexpr int    NPART    = 4096;
static constexpr size_t PART_OFF = BT_OFF + BT_BYTES;
static constexpr size_t SCALE_OFF= PART_OFF + NPART * sizeof(float);

// ------------------------------------------------------------- scale finalize
__global__ __launch_bounds__(TPB) void k_scale(const float* __restrict__ partials,
                                               float* __restrict__ scale) {
    __shared__ float red[TPB];
    float s = 0.f;
    for (int i = threadIdx.x; i < NPART; i += TPB) s += partials[i];
    red[threadIdx.x] = s;
    __syncthreads();
    for (int off = TPB / 2; off > 0; off >>= 1) {
        if ((int)threadIdx.x < off) red[threadIdx.x] += red[threadIdx.x + off];
        __syncthreads();
    }
    if (threadIdx.x == 0) {
        float E = red[0] / (float)((size_t)IN_CH * NUNITS);
        *scale = E / 7.0f;
    }
}

// ------------------------------------------------------------- quantize A
__device__ __forceinline__ unsigned int q4(float4 v) {
    unsigned int b0 = (unsigned int)(int)rintf(fminf(1.0f, fabsf(v.x)) * 7.0f);
    unsigned int b1 = (unsigned int)(int)rintf(fminf(1.0f, fabsf(v.y)) * 7.0f);
    unsigned int b2 = (unsigned int)(int)rintf(fminf(1.0f, fabsf(v.z)) * 7.0f);
    unsigned int b3 = (unsigned int)(int)rintf(fminf(1.0f, fabsf(v.w)) * 7.0f);
    return b0 | (b1 << 8) | (b2 << 16) | (b3 << 24);
}

__global__ __launch_bounds__(TPB) void k_quant_a(const float4* __restrict__ x4,
                                                 uint4* __restrict__ a16) {
    const size_t t = (size_t)blockIdx.x * TPB + threadIdx.x;
    uint4 o;
    o.x = q4(x4[t * 4 + 0]);
    o.y = q4(x4[t * 4 + 1]);
    o.z = q4(x4[t * 4 + 2]);
    o.w = q4(x4[t * 4 + 3]);
    a16[t] = o;
}

// -------------------------- sign(W) transpose to [N][K]  +  fused |W| partial sum
__global__ __launch_bounds__(TPB) void k_signT(const float* __restrict__ W,
                                               char* __restrict__ bt,
                                               float* __restrict__ partials) {
    __shared__ char tile[64][68];
    __shared__ float red[TPB];
    const int bk = blockIdx.x & 63;
    const int bn = blockIdx.x >> 6;
    const int t  = threadIdx.x;
    const int c  = t & 63;
    const int r0 = t >> 6;
    float asum = 0.f;
#pragma unroll
    for (int i = 0; i < 16; ++i) {
        int r = i * 4 + r0;
        float w = W[(size_t)(bk * 64 + r) * NUNITS + bn * 64 + c];
        asum += fabsf(w);
        tile[c][r] = (w > 0.f) ? 1 : ((w < 0.f) ? -1 : 0);
    }
    __syncthreads();
    const int n  = t >> 2;
    const int kk = (t & 3) * 16;
    char o[16];
#pragma unroll
    for (int j = 0; j < 16; ++j) o[j] = tile[n][kk + j];
    *(uint4*)(bt + (size_t)(bn * 64 + n) * IN_CH + bk * 64 + kk) = *(const uint4*)o;

    red[t] = asum;
    __syncthreads();
    for (int off = TPB / 2; off > 0; off >>= 1) {
        if (t < off) red[t] += red[t + off];
        __syncthreads();
    }
    if (t == 0) partials[blockIdx.x] = red[0];
}

// ---------------------------------------------------------------- GEMM
// 256x256 tile, K-tile = 128 B, 8 waves (2Mx4N), mfma_i32_16x16x64_i8.
// m201 8-phase: per phase {quadrant ds-reads, 1 half-tile stage, barrier,
// lgkm0, setprio, 16 MFMA, setprio, barrier}; vmcnt(6) at end-p3/end-p7.
__device__ __forceinline__ void gload_lds16(const void* g, void* l) {
    __builtin_amdgcn_global_load_lds((const __attribute__((address_space(1))) void*)g,
                                     (__attribute__((address_space(3))) void*)l,
                                     16, 0, 0);
}

#define VMCNT6   asm volatile("s_waitcnt vmcnt(6)" ::: "memory")
#define VMCNT0   asm volatile("s_waitcnt vmcnt(0)" ::: "memory")
#define LGKM0    asm volatile("s_waitcnt lgkmcnt(0)" ::: "memory")
#define BARRIER  __builtin_amdgcn_s_barrier()
#define PRIO1    __builtin_amdgcn_s_setprio(1)
#define PRIO0    __builtin_amdgcn_s_setprio(0)

static constexpr int NT = IN_CH / 128;   // 32 K-tiles

__global__ __launch_bounds__(512, 2) void k_gemm(const char* __restrict__ A8,
                                                 const char* __restrict__ BT,
                                                 const float* __restrict__ scale_p,
                                                 const float* __restrict__ bias,
                                                 float* __restrict__ out) {
    __shared__ char As[2][32768];   // [256 rows][128 B], XOR-swizzled
    __shared__ char Bs[2][32768];

    const int t    = threadIdx.x;
    const int bid  = blockIdx.x;                  // 512 blocks
    const int swzb = (bid & 7) * 64 + (bid >> 3); // XCD swizzle (bijective)
    const int bRow = swzb >> 4;
    const int bCol = swzb & 15;
    const int lane = t & 63;
    const int wid  = t >> 6;
    const int wm   = wid >> 2;                    // 0..1
    const int wn   = wid & 3;                     // 0..3
    const int lr   = lane & 15;
    const int lk4  = lane >> 4;

    const size_t aBase = (size_t)(bRow * 256) * IN_CH;
    const size_t bBase = (size_t)(bCol * 256) * IN_CH;

    // swizzled read cols: byte col = s*64 + lk4*16, XOR ((row&7)<<4); row&7 == lr&7
    const int ceff0 = (lk4 * 16) ^ ((lr & 7) << 4);
    const int ceff1 = ceff0 ^ 64;

    // staging: issue q covers rows q*64 + (t>>3), col (t&7)*16 (inverse-swizzled source)
    const int srow  = t >> 3;
    const int scol  = ((t & 7) * 16) ^ ((srow & 7) << 4);
    const int sldso = t * 16;

    v4i acc[8][4] = {};
    v4i a0[4][2], a1[4][2], b01[2][2], b23[2][2];

#define STAGE(kt, q)                                                                  \
    do {                                                                              \
        const int _b = (kt) & 1;                                                      \
        if ((q) < 4)                                                                  \
            gload_lds16(A8 + aBase + (size_t)((q) * 64 + srow) * IN_CH + (kt) * 128 + scol, \
                        &As[_b][(q & 3) * 8192 + sldso]);                             \
        else                                                                          \
            gload_lds16(BT + bBase + (size_t)(((q) - 4) * 64 + srow) * IN_CH + (kt) * 128 + scol, \
                        &Bs[_b][((q) - 4) * 8192 + sldso]);                           \
    } while (0)

#define READ_A0(Ab)                                                    \
    _Pragma("unroll") for (int m = 0; m < 4; ++m) {                    \
        const int ra = (wm * 128 + m * 16 + lr) * 128;                 \
        a0[m][0] = *(const v4i*)((Ab) + ra + ceff0);                   \
        a0[m][1] = *(const v4i*)((Ab) + ra + ceff1);                   \
    }
#define READ_A1(Ab)                                                    \
    _Pragma("unroll") for (int m = 0; m < 4; ++m) {                    \
        const int ra = (wm * 128 + (m + 4) * 16 + lr) * 128;           \
        a1[m][0] = *(const v4i*)((Ab) + ra + ceff0);                   \
        a1[m][1] = *(const v4i*)((Ab) + ra + ceff1);                   \
    }
#define READ_B01(Bb)                                                   \
    _Pragma("unroll") for (int n = 0; n < 2; ++n) {                    \
        const int rb = (wn * 64 + n * 16 + lr) * 128;                  \
        b01[n][0] = *(const v4i*)((Bb) + rb + ceff0);                  \
        b01[n][1] = *(const v4i*)((Bb) + rb + ceff1);                  \
    }
#define READ_B23(Bb)                                                   \
    _Pragma("unroll") for (int n = 0; n < 2; ++n) {                    \
        const int rb = (wn * 64 + (n + 2) * 16 + lr) * 128;            \
        b23[n][0] = *(const v4i*)((Bb) + rb + ceff0);                  \
        b23[n][1] = *(const v4i*)((Bb) + rb + ceff1);                  \
    }
#define MFMA16(arr, brr, mo, no)                                                       \
    PRIO1;                                                                             \
    _Pragma("unroll") for (int m = 0; m < 4; ++m)                                      \
        _Pragma("unroll") for (int n = 0; n < 2; ++n)                                  \
            _Pragma("unroll") for (int s = 0; s < 2; ++s)                              \
                acc[(mo) + m][(no) + n] = __builtin_amdgcn_mfma_i32_16x16x64_i8(       \
                    arr[m][s], brr[n][s], acc[(mo) + m][(no) + n], 0, 0, 0);           \
    PRIO0

    // ---- prologue: T0 full (8 loads) + T1 minus q1,q3 (6 loads) = 14 loads.
    // vmcnt(6) leaves exactly T1's {q0q2,q4q5,q6q7} pending = steady-state invariant.
    STAGE(0, 0); STAGE(0, 1); STAGE(0, 2); STAGE(0, 3);
    STAGE(0, 4); STAGE(0, 5); STAGE(0, 6); STAGE(0, 7);
    STAGE(1, 0); STAGE(1, 2); STAGE(1, 4); STAGE(1, 5); STAGE(1, 6); STAGE(1, 7);
    VMCNT6;
    BARRIER;

    const char* Ab0 = As[0]; const char* Bb0 = Bs[0];
    const char* Ab1 = As[1]; const char* Bb1 = Bs[1];

    for (int i = 0; i < 15; ++i) {
        const int T = 2 * i;
        // p0: tile T quadrant (m0-3 x n0-1); stage (T+1).q1q3 -> buf1 (died last p6)
        READ_A0(Ab0); READ_B01(Bb0);
        STAGE(T + 1, 1); STAGE(T + 1, 3);
        BARRIER; LGKM0;
        MFMA16(a0, b01, 0, 0);
        BARRIER;
        // p1: (m0-3 x n2-3); stage (T+2).q0q2 -> buf0 (died at p0)
        READ_B23(Bb0);
        STAGE(T + 2, 0); STAGE(T + 2, 2);
        BARRIER; LGKM0;
        MFMA16(a0, b23, 0, 2);
        BARRIER;
        // p2: (m4-7 x n0-1); stage (T+2).q4q5 (B-lo, died at p1)
        READ_A1(Ab0);
        STAGE(T + 2, 4); STAGE(T + 2, 5);
        BARRIER; LGKM0;
        MFMA16(a1, b01, 4, 0);
        BARRIER;
        // p3: (m4-7 x n2-3); stage (T+2).q6q7 (B-hi, died at p1); GATE
        STAGE(T + 2, 6); STAGE(T + 2, 7);
        VMCNT6;
        BARRIER;
        MFMA16(a1, b23, 4, 2);
        BARRIER;
        // p4: tile T+1; stage (T+2).q1q3 (A-odd, died at p2)
        READ_A0(Ab1); READ_B01(Bb1);
        STAGE(T + 2, 1); STAGE(T + 2, 3);
        BARRIER; LGKM0;
        MFMA16(a0, b01, 0, 0);
        BARRIER;
        // p5: stage (T+3).q0q2 -> buf1 (died at p4)
        READ_B23(Bb1);
        STAGE(T + 3, 0); STAGE(T + 3, 2);
        BARRIER; LGKM0;
        MFMA16(a0, b23, 0, 2);
        BARRIER;
        // p6: stage (T+3).q4q5
        READ_A1(Ab1);
        STAGE(T + 3, 4); STAGE(T + 3, 5);
        BARRIER; LGKM0;
        MFMA16(a1, b01, 4, 0);
        BARRIER;
        // p7: stage (T+3).q6q7; GATE
        STAGE(T + 3, 6); STAGE(T + 3, 7);
        VMCNT6;
        BARRIER;
        MFMA16(a1, b23, 4, 2);
        BARRIER;
    }

    // ---- tail: T = 30 (tiles 30, 31)
    READ_A0(Ab0); READ_B01(Bb0);
    STAGE(31, 1); STAGE(31, 3);
    BARRIER; LGKM0;
    MFMA16(a0, b01, 0, 0);
    BARRIER;
    READ_B23(Bb0);
    BARRIER; LGKM0;
    MFMA16(a0, b23, 0, 2);
    BARRIER;
    READ_A1(Ab0);
    BARRIER; LGKM0;
    MFMA16(a1, b01, 4, 0);
    BARRIER;
    VMCNT0;                       // force tile 31's q1q3 (and all else) landed
    BARRIER;
    MFMA16(a1, b23, 4, 2);
    BARRIER;
    READ_A0(Ab1); READ_B01(Bb1);
    BARRIER; LGKM0;
    MFMA16(a0, b01, 0, 0);
    BARRIER;
    READ_B23(Bb1);
    BARRIER; LGKM0;
    MFMA16(a0, b23, 0, 2);
    BARRIER;
    READ_A1(Ab1);
    BARRIER; LGKM0;
    MFMA16(a1, b01, 4, 0);
    MFMA16(a1, b23, 4, 2);

    // ---- epilogue
    const float scale = *scale_p;
    const int orow0 = bRow * 256 + wm * 128;
    const int ocol0 = bCol * 256 + wn * 64;
#pragma unroll
    for (int m = 0; m < 8; ++m) {
#pragma unroll
        for (int n = 0; n < 4; ++n) {
            const int col = ocol0 + n * 16 + lr;
            const float bb = bias[col];
            const int rbase = orow0 + m * 16 + lk4 * 4;
#pragma unroll
            for (int j = 0; j < 4; ++j)
                out[(size_t)(rbase + j) * NUNITS + col] = scale * (float)acc[m][n][j] + bb;
        }
    }
#undef STAGE
#undef READ_A0
#undef READ_A1
#undef READ_B01
#undef READ_B23
#undef MFMA16
}

// ---------------------------------------------------------------- launch
extern "C" void kernel_launch(void* const* d_in, const int* in_sizes, int n_in,
                              void* d_out, int out_size, void* d_ws, size_t ws_size,
                              hipStream_t stream) {
    const float* x  = (const float*)d_in[0];
    const float* W  = (const float*)d_in[1];
    const float* b  = (const float*)d_in[2];
    float* out      = (float*)d_out;

    char*  ws       = (char*)d_ws;
    char*  A8       = ws + A8_OFF;
    char*  BT       = ws + BT_OFF;
    float* partials = (float*)(ws + PART_OFF);
    float* scale    = (float*)(ws + SCALE_OFF);

    k_signT<<<(IN_CH / 64) * (NUNITS / 64), TPB, 0, stream>>>(W, BT, partials);
    k_scale<<<1, TPB, 0, stream>>>(partials, scale);
    k_quant_a<<<(BATCH * (IN_CH / 16)) / TPB, TPB, 0, stream>>>((const float4*)x, (uint4*)A8);
    k_gemm<<<(BATCH / 256) * (NUNITS / 256), 512, 0, stream>>>(A8, BT, scale, b, out);
}